// Round 3
// baseline (3014.069 us; speedup 1.0000x reference)
//
#include <hip/hip_runtime.h>
#include <cstddef>

#define NN 20000
#define NE 320000

// ---------------- edge-index layout detection ----------------
// If the buffer is int64 (2,NE) row-major, every int64-read in [0,NE) is a
// valid node id. If it is int32, int64 reads combine two int32s -> huge values.
__global__ __launch_bounds__(256) void detect_kernel(const void* __restrict__ edges, int* flag) {
    int i = blockIdx.x * blockDim.x + threadIdx.x;
    if (i >= NE) return;
    long long v = ((const long long*)edges)[i];
    if (v < 0 || v >= NN) atomicOr(flag, 1);   // flag=1 -> int32 layout
}

__global__ __launch_bounds__(256) void convert_kernel(const void* __restrict__ edges,
                                                      const int* __restrict__ flag,
                                                      int* __restrict__ src, int* __restrict__ dst,
                                                      float* __restrict__ deg) {
    int i = blockIdx.x * blockDim.x + threadIdx.x;
    if (i >= NE) return;
    int s, d;
    if (*flag) {  // int32 layout
        s = ((const int*)edges)[i];
        d = ((const int*)edges)[NE + i];
    } else {      // int64 layout
        s = (int)((const long long*)edges)[i];
        d = (int)((const long long*)edges)[NE + i];
    }
    src[i] = s;
    dst[i] = d;
    atomicAdd(&deg[d], 1.0f);   // exact: integer-valued fp32 sums < 2^24
}

// ---------------- segment-sum scatter ----------------
template <int D>
__global__ __launch_bounds__(256) void scatter_kernel(const float* __restrict__ feat,
                                                      const int* __restrict__ src,
                                                      const int* __restrict__ dst,
                                                      float* __restrict__ out) {
    constexpr int GROUP = D / 4;       // lanes per edge (float4 each)
    constexpr int EPB = 256 / GROUP;   // edges per block
    int t = threadIdx.x;
    int e = blockIdx.x * EPB + t / GROUP;
    if (e >= NE) return;
    int c = (t % GROUP) * 4;
    int s = src[e], d = dst[e];
    float4 v = *(const float4*)(feat + (size_t)s * D + c);
    float* o = out + (size_t)d * D + c;
    atomicAdd(o + 0, v.x);
    atomicAdd(o + 1, v.y);
    atomicAdd(o + 2, v.z);
    atomicAdd(o + 3, v.w);
}

// ---------------- mean-normalize rows ----------------
template <int D>
__global__ __launch_bounds__(256) void normalize_kernel(float* __restrict__ s,
                                                        const float* __restrict__ deg) {
    constexpr int G = D / 4;
    int idx = blockIdx.x * blockDim.x + threadIdx.x;
    if (idx >= NN * G) return;
    int row = idx / G;
    int c = (idx % G) * 4;
    float inv = 1.0f / fmaxf(deg[row], 1.0f);
    float4* p = (float4*)(s + (size_t)row * D + c);
    float4 v = *p;
    v.x *= inv; v.y *= inv; v.z *= inv; v.w *= inv;
    *p = v;
}

// ---------------- dual GEMM: C = act(A0@B0 + A1@B1 + bias) (+ res) ----------------
// A: M x K row-major, B: K x N row-major, C: M x N row-major. K%16==0, N%64==0.
template <int RELU, int HAS_RES>
__global__ __launch_bounds__(256) void gemm_dual(const float* __restrict__ A0,
                                                 const float* __restrict__ B0, int K0,
                                                 const float* __restrict__ A1,
                                                 const float* __restrict__ B1, int K1,
                                                 const float* __restrict__ bias,
                                                 const float* __restrict__ res,
                                                 float* __restrict__ C, int M, int N) {
    __shared__ float As[16][64];   // transposed A tile: As[k][m]
    __shared__ float Bs[16][64];   // Bs[k][n]

    int t = threadIdx.x;
    int rowBase = blockIdx.x * 64;
    int colBase = blockIdx.y * 64;

    int la_r = t >> 2;            // 0..63
    int la_c = (t & 3) * 4;       // 0,4,8,12
    int lb_r = t >> 4;            // 0..15
    int lb_c = (t & 15) * 4;      // 0..60

    int ty = t >> 4;              // 0..15 -> rows ty*4..+4
    int tx = t & 15;              // 0..15 -> cols tx*4..+4

    float acc[4][4];
#pragma unroll
    for (int i = 0; i < 4; i++)
#pragma unroll
        for (int j = 0; j < 4; j++) acc[i][j] = 0.0f;

    for (int phase = 0; phase < 2; phase++) {
        const float* A = phase ? A1 : A0;
        const float* B = phase ? B1 : B0;
        int K = phase ? K1 : K0;
        if (A == nullptr || K == 0) continue;

        for (int k0 = 0; k0 < K; k0 += 16) {
            int arow = rowBase + la_r;
            float4 av = make_float4(0.f, 0.f, 0.f, 0.f);
            if (arow < M) av = *(const float4*)(A + (size_t)arow * K + k0 + la_c);
            float4 bv = *(const float4*)(B + (size_t)(k0 + lb_r) * N + colBase + lb_c);

            __syncthreads();
            As[la_c + 0][la_r] = av.x;
            As[la_c + 1][la_r] = av.y;
            As[la_c + 2][la_r] = av.z;
            As[la_c + 3][la_r] = av.w;
            *(float4*)&Bs[lb_r][lb_c] = bv;
            __syncthreads();

#pragma unroll
            for (int k = 0; k < 16; k++) {
                float a[4], b[4];
#pragma unroll
                for (int i = 0; i < 4; i++) a[i] = As[k][ty * 4 + i];
#pragma unroll
                for (int j = 0; j < 4; j++) b[j] = Bs[k][tx * 4 + j];
#pragma unroll
                for (int i = 0; i < 4; i++)
#pragma unroll
                    for (int j = 0; j < 4; j++) acc[i][j] += a[i] * b[j];
            }
        }
    }

    float4 bv = *(const float4*)(bias + colBase + tx * 4);
#pragma unroll
    for (int i = 0; i < 4; i++) {
        int row = rowBase + ty * 4 + i;
        if (row >= M) continue;
        float4 v;
        v.x = acc[i][0] + bv.x;
        v.y = acc[i][1] + bv.y;
        v.z = acc[i][2] + bv.z;
        v.w = acc[i][3] + bv.w;
        if (RELU) {
            v.x = fmaxf(v.x, 0.f); v.y = fmaxf(v.y, 0.f);
            v.z = fmaxf(v.z, 0.f); v.w = fmaxf(v.w, 0.f);
        }
        if (HAS_RES) {
            float4 r = *(const float4*)(res + (size_t)row * N + colBase + tx * 4);
            v.x += r.x; v.y += r.y; v.z += r.z; v.w += r.w;
        }
        *(float4*)(C + (size_t)row * N + colBase + tx * 4) = v;
    }
}

extern "C" void kernel_launch(void* const* d_in, const int* in_sizes, int n_in,
                              void* d_out, int out_size, void* d_ws, size_t ws_size,
                              hipStream_t stream) {
    const float* x    = (const float*)d_in[0];
    const void*  edges = d_in[1];
    const float* W1l  = (const float*)d_in[2];
    const float* b1   = (const float*)d_in[3];
    const float* W1r  = (const float*)d_in[4];
    const float* W2l  = (const float*)d_in[5];
    const float* b2   = (const float*)d_in[6];
    const float* W2r  = (const float*)d_in[7];
    const float* Wres = (const float*)d_in[8];
    const float* bres = (const float*)d_in[9];
    const float* Wmul = (const float*)d_in[10];
    const float* bmu  = (const float*)d_in[11];
    const float* Wmur = (const float*)d_in[12];
    const float* Wlsl = (const float*)d_in[13];
    const float* bls  = (const float*)d_in[14];
    const float* Wlsr = (const float*)d_in[15];
    float* out = (float*)d_out;

    char* ws = (char*)d_ws;
    size_t off = 0;
    int* flag = (int*)(ws + off); off += 256;
    int* src  = (int*)(ws + off); off += (size_t)NE * 4;
    int* dst  = (int*)(ws + off); off += (size_t)NE * 4;
    float* deg = (float*)(ws + off); off += (size_t)NN * 4;
    off = (off + 255) & ~(size_t)255;
    float* bufA = (float*)(ws + off); off += (size_t)NN * 256 * 4;  // s1/agg1, then xres
    float* h1   = (float*)(ws + off); off += (size_t)NN * 256 * 4;
    float* bufB = (float*)(ws + off); off += (size_t)NN * 256 * 4;  // s2/agg2, then s3/agg3
    float* h2   = (float*)(ws + off); off += (size_t)NN * 256 * 4;

    hipMemsetAsync(flag, 0, 4, stream);
    hipMemsetAsync(deg, 0, (size_t)NN * 4, stream);
    hipMemsetAsync(bufA, 0, (size_t)NN * 128 * 4, stream);

    detect_kernel<<<NE / 256, 256, 0, stream>>>(edges, flag);
    convert_kernel<<<NE / 256, 256, 0, stream>>>(edges, flag, src, dst, deg);

    // layer 1: agg1 = mean_scatter(x) ; h1 = relu(agg1@W1l + b1 + x@W1r)
    scatter_kernel<128><<<NE / 8, 256, 0, stream>>>(x, src, dst, bufA);
    normalize_kernel<128><<<(NN * 32 + 255) / 256, 256, 0, stream>>>(bufA, deg);
    gemm_dual<1, 0><<<dim3(313, 4), 256, 0, stream>>>(bufA, W1l, 128, x, W1r, 128, b1, nullptr, h1, NN, 256);

    // xres = x@Wres + bres  (into bufA, agg1 no longer needed)
    gemm_dual<0, 0><<<dim3(313, 4), 256, 0, stream>>>(x, Wres, 128, nullptr, nullptr, 0, bres, nullptr, bufA, NN, 256);

    // layer 2: agg2 = mean_scatter(h1) ; h2 = relu(agg2@W2l + b2 + h1@W2r) + xres
    hipMemsetAsync(bufB, 0, (size_t)NN * 256 * 4, stream);
    scatter_kernel<256><<<NE / 4, 256, 0, stream>>>(h1, src, dst, bufB);
    normalize_kernel<256><<<(NN * 64 + 255) / 256, 256, 0, stream>>>(bufB, deg);
    gemm_dual<1, 1><<<dim3(313, 4), 256, 0, stream>>>(bufB, W2l, 256, h1, W2r, 256, b2, bufA, h2, NN, 256);

    // layer 3: agg3 = mean_scatter(h2) ; mu & logstd
    hipMemsetAsync(bufB, 0, (size_t)NN * 256 * 4, stream);
    scatter_kernel<256><<<NE / 4, 256, 0, stream>>>(h2, src, dst, bufB);
    normalize_kernel<256><<<(NN * 64 + 255) / 256, 256, 0, stream>>>(bufB, deg);
    gemm_dual<0, 0><<<dim3(313, 1), 256, 0, stream>>>(bufB, Wmul, 256, h2, Wmur, 256, bmu, nullptr, out, NN, 64);
    gemm_dual<0, 0><<<dim3(313, 1), 256, 0, stream>>>(bufB, Wlsl, 256, h2, Wlsr, 256, bls, nullptr,
                                                      out + (size_t)NN * 64, NN, 64);
}

// Round 4
// 528.355 us; speedup vs baseline: 5.7046x; 5.7046x over previous
//
#include <hip/hip_runtime.h>
#include <cstddef>

#define NN 20000
#define NE 320000

// ---------------- edge-index layout detection ----------------
__global__ __launch_bounds__(256) void detect_kernel(const void* __restrict__ edges, int* flag) {
    int i = blockIdx.x * blockDim.x + threadIdx.x;
    if (i >= NE) return;
    long long v = ((const long long*)edges)[i];
    if (v < 0 || v >= NN) atomicOr(flag, 1);   // flag=1 -> int32 layout
}

// extract src/dst + integer degree count
__global__ __launch_bounds__(256) void convert_kernel(const void* __restrict__ edges,
                                                      const int* __restrict__ flag,
                                                      int* __restrict__ src, int* __restrict__ dst,
                                                      int* __restrict__ deg) {
    int i = blockIdx.x * blockDim.x + threadIdx.x;
    if (i >= NE) return;
    int s, d;
    if (*flag) {  // int32 layout
        s = ((const int*)edges)[i];
        d = ((const int*)edges)[NE + i];
    } else {      // int64 layout
        s = (int)((const long long*)edges)[i];
        d = (int)((const long long*)edges)[NE + i];
    }
    src[i] = s;
    dst[i] = d;
    atomicAdd(&deg[d], 1);
}

// ---------------- one-block exclusive scan: rowptr = exscan(deg) ----------------
__global__ __launch_bounds__(256) void scan_kernel(const int* __restrict__ deg,
                                                   int* __restrict__ rowptr) {
    __shared__ int buf[256];
    __shared__ int carry_s;
    int t = threadIdx.x;
    if (t == 0) carry_s = 0;
    __syncthreads();
    for (int base = 0; base < NN; base += 256) {
        int i = base + t;
        int v = (i < NN) ? deg[i] : 0;
        int carry = carry_s;
        buf[t] = v;
        __syncthreads();
        for (int off = 1; off < 256; off <<= 1) {
            int u = (t >= off) ? buf[t - off] : 0;
            __syncthreads();
            buf[t] += u;
            __syncthreads();
        }
        if (i < NN) rowptr[i] = carry + buf[t] - v;   // exclusive
        __syncthreads();
        if (t == 0) carry_s = carry + buf[255];
        __syncthreads();
    }
    if (t == 0) rowptr[NN] = carry_s;   // == NE
}

// ---------------- CSR fill ----------------
__global__ __launch_bounds__(256) void fill_kernel(const int* __restrict__ src,
                                                   const int* __restrict__ dst,
                                                   const int* __restrict__ rowptr,
                                                   int* __restrict__ cursor,
                                                   int* __restrict__ csr_src) {
    int i = blockIdx.x * blockDim.x + threadIdx.x;
    if (i >= NE) return;
    int d = dst[i];
    int p = atomicAdd(&cursor[d], 1);
    csr_src[rowptr[d] + p] = src[i];
}

// ---------------- CSR mean-aggregate: one wave per node ----------------
template <int D>
__global__ __launch_bounds__(256) void aggregate_kernel(const float* __restrict__ feat,
                                                        const int* __restrict__ csr_src,
                                                        const int* __restrict__ rowptr,
                                                        float* __restrict__ out) {
    constexpr int V = D / 64;   // floats per lane: 2 (D=128) or 4 (D=256)
    int node = blockIdx.x * 4 + (threadIdx.x >> 6);
    if (node >= NN) return;
    int lane = threadIdx.x & 63;
    int beg = rowptr[node], end = rowptr[node + 1];

    if constexpr (V == 4) {
        float4 a0 = make_float4(0.f, 0.f, 0.f, 0.f);
        float4 a1 = make_float4(0.f, 0.f, 0.f, 0.f);
        int e = beg;
        for (; e + 1 < end; e += 2) {
            int s0 = csr_src[e], s1 = csr_src[e + 1];
            float4 v0 = *(const float4*)(feat + (size_t)s0 * D + lane * 4);
            float4 v1 = *(const float4*)(feat + (size_t)s1 * D + lane * 4);
            a0.x += v0.x; a0.y += v0.y; a0.z += v0.z; a0.w += v0.w;
            a1.x += v1.x; a1.y += v1.y; a1.z += v1.z; a1.w += v1.w;
        }
        if (e < end) {
            int s0 = csr_src[e];
            float4 v0 = *(const float4*)(feat + (size_t)s0 * D + lane * 4);
            a0.x += v0.x; a0.y += v0.y; a0.z += v0.z; a0.w += v0.w;
        }
        float inv = 1.0f / (float)max(end - beg, 1);
        float4 r;
        r.x = (a0.x + a1.x) * inv;
        r.y = (a0.y + a1.y) * inv;
        r.z = (a0.z + a1.z) * inv;
        r.w = (a0.w + a1.w) * inv;
        *(float4*)(out + (size_t)node * D + lane * 4) = r;
    } else {
        float2 a0 = make_float2(0.f, 0.f);
        float2 a1 = make_float2(0.f, 0.f);
        int e = beg;
        for (; e + 1 < end; e += 2) {
            int s0 = csr_src[e], s1 = csr_src[e + 1];
            float2 v0 = *(const float2*)(feat + (size_t)s0 * D + lane * 2);
            float2 v1 = *(const float2*)(feat + (size_t)s1 * D + lane * 2);
            a0.x += v0.x; a0.y += v0.y;
            a1.x += v1.x; a1.y += v1.y;
        }
        if (e < end) {
            int s0 = csr_src[e];
            float2 v0 = *(const float2*)(feat + (size_t)s0 * D + lane * 2);
            a0.x += v0.x; a0.y += v0.y;
        }
        float inv = 1.0f / (float)max(end - beg, 1);
        float2 r;
        r.x = (a0.x + a1.x) * inv;
        r.y = (a0.y + a1.y) * inv;
        *(float2*)(out + (size_t)node * D + lane * 2) = r;
    }
}

// ---------------- dual GEMM: C = act(A0@B0 + A1@B1 + bias) (+ res) ----------------
template <int RELU, int HAS_RES>
__global__ __launch_bounds__(256) void gemm_dual(const float* __restrict__ A0,
                                                 const float* __restrict__ B0, int K0,
                                                 const float* __restrict__ A1,
                                                 const float* __restrict__ B1, int K1,
                                                 const float* __restrict__ bias,
                                                 const float* __restrict__ res,
                                                 float* __restrict__ C, int M, int N) {
    __shared__ float As[16][64];   // As[k][m]
    __shared__ float Bs[16][64];   // Bs[k][n]

    int t = threadIdx.x;
    int rowBase = blockIdx.x * 64;
    int colBase = blockIdx.y * 64;

    int la_r = t >> 2;
    int la_c = (t & 3) * 4;
    int lb_r = t >> 4;
    int lb_c = (t & 15) * 4;

    int ty = t >> 4;
    int tx = t & 15;

    float acc[4][4];
#pragma unroll
    for (int i = 0; i < 4; i++)
#pragma unroll
        for (int j = 0; j < 4; j++) acc[i][j] = 0.0f;

    for (int phase = 0; phase < 2; phase++) {
        const float* A = phase ? A1 : A0;
        const float* B = phase ? B1 : B0;
        int K = phase ? K1 : K0;
        if (A == nullptr || K == 0) continue;

        for (int k0 = 0; k0 < K; k0 += 16) {
            int arow = rowBase + la_r;
            float4 av = make_float4(0.f, 0.f, 0.f, 0.f);
            if (arow < M) av = *(const float4*)(A + (size_t)arow * K + k0 + la_c);
            float4 bv = *(const float4*)(B + (size_t)(k0 + lb_r) * N + colBase + lb_c);

            __syncthreads();
            As[la_c + 0][la_r] = av.x;
            As[la_c + 1][la_r] = av.y;
            As[la_c + 2][la_r] = av.z;
            As[la_c + 3][la_r] = av.w;
            *(float4*)&Bs[lb_r][lb_c] = bv;
            __syncthreads();

#pragma unroll
            for (int k = 0; k < 16; k++) {
                float a[4], b[4];
#pragma unroll
                for (int i = 0; i < 4; i++) a[i] = As[k][ty * 4 + i];
#pragma unroll
                for (int j = 0; j < 4; j++) b[j] = Bs[k][tx * 4 + j];
#pragma unroll
                for (int i = 0; i < 4; i++)
#pragma unroll
                    for (int j = 0; j < 4; j++) acc[i][j] += a[i] * b[j];
            }
        }
    }

    float4 bv = *(const float4*)(bias + colBase + tx * 4);
#pragma unroll
    for (int i = 0; i < 4; i++) {
        int row = rowBase + ty * 4 + i;
        if (row >= M) continue;
        float4 v;
        v.x = acc[i][0] + bv.x;
        v.y = acc[i][1] + bv.y;
        v.z = acc[i][2] + bv.z;
        v.w = acc[i][3] + bv.w;
        if (RELU) {
            v.x = fmaxf(v.x, 0.f); v.y = fmaxf(v.y, 0.f);
            v.z = fmaxf(v.z, 0.f); v.w = fmaxf(v.w, 0.f);
        }
        if (HAS_RES) {
            float4 r = *(const float4*)(res + (size_t)row * N + colBase + tx * 4);
            v.x += r.x; v.y += r.y; v.z += r.z; v.w += r.w;
        }
        *(float4*)(C + (size_t)row * N + colBase + tx * 4) = v;
    }
}

extern "C" void kernel_launch(void* const* d_in, const int* in_sizes, int n_in,
                              void* d_out, int out_size, void* d_ws, size_t ws_size,
                              hipStream_t stream) {
    const float* x    = (const float*)d_in[0];
    const void*  edges = d_in[1];
    const float* W1l  = (const float*)d_in[2];
    const float* b1   = (const float*)d_in[3];
    const float* W1r  = (const float*)d_in[4];
    const float* W2l  = (const float*)d_in[5];
    const float* b2   = (const float*)d_in[6];
    const float* W2r  = (const float*)d_in[7];
    const float* Wres = (const float*)d_in[8];
    const float* bres = (const float*)d_in[9];
    const float* Wmul = (const float*)d_in[10];
    const float* bmu  = (const float*)d_in[11];
    const float* Wmur = (const float*)d_in[12];
    const float* Wlsl = (const float*)d_in[13];
    const float* bls  = (const float*)d_in[14];
    const float* Wlsr = (const float*)d_in[15];
    float* out = (float*)d_out;

    char* ws = (char*)d_ws;
    size_t off = 0;
    int* flag    = (int*)(ws + off); off += 256;
    int* src     = (int*)(ws + off); off += (size_t)NE * 4;
    int* dst     = (int*)(ws + off); off += (size_t)NE * 4;
    int* csr_src = (int*)(ws + off); off += (size_t)NE * 4;
    int* deg     = (int*)(ws + off); off += (size_t)NN * 4;
    int* rowptr  = (int*)(ws + off); off += (size_t)(NN + 1) * 4;
    int* cursor  = (int*)(ws + off); off += (size_t)NN * 4;
    off = (off + 255) & ~(size_t)255;
    float* bufA = (float*)(ws + off); off += (size_t)NN * 256 * 4;  // agg1, then xres
    float* h1   = (float*)(ws + off); off += (size_t)NN * 256 * 4;
    float* bufB = (float*)(ws + off); off += (size_t)NN * 256 * 4;  // agg2, then agg3
    float* h2   = (float*)(ws + off); off += (size_t)NN * 256 * 4;

    hipMemsetAsync(flag, 0, 4, stream);
    hipMemsetAsync(deg, 0, (size_t)NN * 4, stream);
    hipMemsetAsync(cursor, 0, (size_t)NN * 4, stream);

    detect_kernel<<<NE / 256, 256, 0, stream>>>(edges, flag);
    convert_kernel<<<NE / 256, 256, 0, stream>>>(edges, flag, src, dst, deg);
    scan_kernel<<<1, 256, 0, stream>>>(deg, rowptr);
    fill_kernel<<<NE / 256, 256, 0, stream>>>(src, dst, rowptr, cursor, csr_src);

    // layer 1: agg1 = csr_mean(x) ; h1 = relu(agg1@W1l + b1 + x@W1r)
    aggregate_kernel<128><<<NN / 4, 256, 0, stream>>>(x, csr_src, rowptr, bufA);
    gemm_dual<1, 0><<<dim3(313, 4), 256, 0, stream>>>(bufA, W1l, 128, x, W1r, 128, b1, nullptr, h1, NN, 256);

    // xres = x@Wres + bres  (into bufA)
    gemm_dual<0, 0><<<dim3(313, 4), 256, 0, stream>>>(x, Wres, 128, nullptr, nullptr, 0, bres, nullptr, bufA, NN, 256);

    // layer 2: agg2 = csr_mean(h1) ; h2 = relu(agg2@W2l + b2 + h1@W2r) + xres
    aggregate_kernel<256><<<NN / 4, 256, 0, stream>>>(h1, csr_src, rowptr, bufB);
    gemm_dual<1, 1><<<dim3(313, 4), 256, 0, stream>>>(bufB, W2l, 256, h1, W2r, 256, b2, bufA, h2, NN, 256);

    // layer 3: agg3 = csr_mean(h2) shared by mu & logstd
    aggregate_kernel<256><<<NN / 4, 256, 0, stream>>>(h2, csr_src, rowptr, bufB);
    gemm_dual<0, 0><<<dim3(313, 1), 256, 0, stream>>>(bufB, Wmul, 256, h2, Wmur, 256, bmu, nullptr, out, NN, 64);
    gemm_dual<0, 0><<<dim3(313, 1), 256, 0, stream>>>(bufB, Wlsl, 256, h2, Wlsr, 256, bls, nullptr,
                                                      out + (size_t)NN * 64, NN, 64);
}

// Round 5
// 349.944 us; speedup vs baseline: 8.6130x; 1.5098x over previous
//
#include <hip/hip_runtime.h>
#include <cstddef>

#define NN 20000
#define NE 320000

typedef short bf16x8 __attribute__((ext_vector_type(8)));
typedef float f32x4 __attribute__((ext_vector_type(4)));

__device__ __forceinline__ float bf2f(unsigned short u) {
    unsigned x = ((unsigned)u) << 16;
    return __builtin_bit_cast(float, x);
}
__device__ __forceinline__ unsigned short f2bf(float f) {
    unsigned x = __builtin_bit_cast(unsigned, f);
    x = (x + 0x7fff + ((x >> 16) & 1)) >> 16;   // round-to-nearest-even
    return (unsigned short)x;
}

// ---------------- edge-index layout detection ----------------
__global__ __launch_bounds__(256) void detect_kernel(const void* __restrict__ edges, int* flag) {
    int i = blockIdx.x * blockDim.x + threadIdx.x;
    if (i >= NE) return;
    long long v = ((const long long*)edges)[i];
    if (v < 0 || v >= NN) atomicOr(flag, 1);   // flag=1 -> int32 layout
}

__global__ __launch_bounds__(256) void convert_kernel(const void* __restrict__ edges,
                                                      const int* __restrict__ flag,
                                                      int* __restrict__ src, int* __restrict__ dst,
                                                      int* __restrict__ deg) {
    int i = blockIdx.x * blockDim.x + threadIdx.x;
    if (i >= NE) return;
    int s, d;
    if (*flag) {
        s = ((const int*)edges)[i];
        d = ((const int*)edges)[NE + i];
    } else {
        s = (int)((const long long*)edges)[i];
        d = (int)((const long long*)edges)[NE + i];
    }
    src[i] = s;
    dst[i] = d;
    atomicAdd(&deg[d], 1);
}

// ---------------- parallel exclusive scan (3 phases) ----------------
__global__ __launch_bounds__(256) void scan1_kernel(const int* __restrict__ deg,
                                                    int* __restrict__ incl, int* __restrict__ bsum) {
    __shared__ int buf[256];
    int t = threadIdx.x, i = blockIdx.x * 256 + t;
    int v = (i < NN) ? deg[i] : 0;
    buf[t] = v;
    __syncthreads();
    for (int off = 1; off < 256; off <<= 1) {
        int u = (t >= off) ? buf[t - off] : 0;
        __syncthreads();
        buf[t] += u;
        __syncthreads();
    }
    if (i < NN) incl[i] = buf[t];
    if (t == 255) bsum[blockIdx.x] = buf[255];
}

__global__ __launch_bounds__(256) void scan2_kernel(const int* __restrict__ bsum,
                                                    int* __restrict__ boff) {
    __shared__ int buf[256];
    const int nb = (NN + 255) / 256;   // 79
    int t = threadIdx.x;
    int v = (t < nb) ? bsum[t] : 0;
    buf[t] = v;
    __syncthreads();
    for (int off = 1; off < 256; off <<= 1) {
        int u = (t >= off) ? buf[t - off] : 0;
        __syncthreads();
        buf[t] += u;
        __syncthreads();
    }
    if (t < nb) boff[t] = buf[t] - v;   // exclusive
}

__global__ __launch_bounds__(256) void scan3_kernel(const int* __restrict__ deg,
                                                    const int* __restrict__ incl,
                                                    const int* __restrict__ boff,
                                                    int* __restrict__ rowptr) {
    int i = blockIdx.x * 256 + threadIdx.x;
    if (i < NN) rowptr[i] = boff[i >> 8] + incl[i] - deg[i];
    if (i == NN) rowptr[NN] = NE;
}

// ---------------- CSR fill ----------------
__global__ __launch_bounds__(256) void fill_kernel(const int* __restrict__ src,
                                                   const int* __restrict__ dst,
                                                   const int* __restrict__ rowptr,
                                                   int* __restrict__ cursor,
                                                   int* __restrict__ csr_src) {
    int i = blockIdx.x * blockDim.x + threadIdx.x;
    if (i >= NE) return;
    int d = dst[i];
    int p = atomicAdd(&cursor[d], 1);
    csr_src[rowptr[d] + p] = src[i];
}

// ---------------- fp32 -> bf16 cast ----------------
__global__ __launch_bounds__(256) void cast_kernel(const float* __restrict__ in,
                                                   unsigned short* __restrict__ out, int n4) {
    int i = blockIdx.x * 256 + threadIdx.x;
    if (i >= n4) return;
    float4 v = *(const float4*)(in + (size_t)i * 4);
    ushort4 o;
    o.x = f2bf(v.x); o.y = f2bf(v.y); o.z = f2bf(v.z); o.w = f2bf(v.w);
    *(ushort4*)(out + (size_t)i * 4) = o;
}

// ---------------- weight transpose+cast: W[K][N] f32 -> WT[N][K] bf16 ----------------
__global__ __launch_bounds__(256) void wtrans_kernel(const float* __restrict__ W,
                                                     unsigned short* __restrict__ WT, int K, int N) {
    int i = blockIdx.x * 256 + threadIdx.x;
    if (i >= K * N) return;
    int k = i / N, n = i % N;
    WT[(size_t)n * K + k] = f2bf(W[i]);
}

// ---------------- CSR mean-aggregate (bf16 in/out, fp32 accum) ----------------
template <int D>
__global__ __launch_bounds__(256) void aggregate_kernel(const unsigned short* __restrict__ feat,
                                                        const int* __restrict__ csr_src,
                                                        const int* __restrict__ rowptr,
                                                        unsigned short* __restrict__ out) {
    int node = blockIdx.x * 4 + (threadIdx.x >> 6);
    if (node >= NN) return;
    int lane = threadIdx.x & 63;
    int beg = rowptr[node], end = rowptr[node + 1];
    int cnt = end - beg;
    float inv = 1.0f / (float)(cnt > 0 ? cnt : 1);

    if constexpr (D == 256) {
        float a0[4] = {0.f, 0.f, 0.f, 0.f}, a1[4] = {0.f, 0.f, 0.f, 0.f};
        int e = beg;
        for (; e + 1 < end; e += 2) {
            int s0 = csr_src[e], s1 = csr_src[e + 1];
            ushort4 u0 = *(const ushort4*)(feat + (size_t)s0 * D + lane * 4);
            ushort4 u1 = *(const ushort4*)(feat + (size_t)s1 * D + lane * 4);
            a0[0] += bf2f(u0.x); a0[1] += bf2f(u0.y); a0[2] += bf2f(u0.z); a0[3] += bf2f(u0.w);
            a1[0] += bf2f(u1.x); a1[1] += bf2f(u1.y); a1[2] += bf2f(u1.z); a1[3] += bf2f(u1.w);
        }
        if (e < end) {
            int s0 = csr_src[e];
            ushort4 u0 = *(const ushort4*)(feat + (size_t)s0 * D + lane * 4);
            a0[0] += bf2f(u0.x); a0[1] += bf2f(u0.y); a0[2] += bf2f(u0.z); a0[3] += bf2f(u0.w);
        }
        ushort4 o;
        o.x = f2bf((a0[0] + a1[0]) * inv);
        o.y = f2bf((a0[1] + a1[1]) * inv);
        o.z = f2bf((a0[2] + a1[2]) * inv);
        o.w = f2bf((a0[3] + a1[3]) * inv);
        *(ushort4*)(out + (size_t)node * D + lane * 4) = o;
    } else {   // D == 128
        float a0[2] = {0.f, 0.f}, a1[2] = {0.f, 0.f};
        int e = beg;
        for (; e + 1 < end; e += 2) {
            int s0 = csr_src[e], s1 = csr_src[e + 1];
            ushort2 u0 = *(const ushort2*)(feat + (size_t)s0 * D + lane * 2);
            ushort2 u1 = *(const ushort2*)(feat + (size_t)s1 * D + lane * 2);
            a0[0] += bf2f(u0.x); a0[1] += bf2f(u0.y);
            a1[0] += bf2f(u1.x); a1[1] += bf2f(u1.y);
        }
        if (e < end) {
            int s0 = csr_src[e];
            ushort2 u0 = *(const ushort2*)(feat + (size_t)s0 * D + lane * 2);
            a0[0] += bf2f(u0.x); a0[1] += bf2f(u0.y);
        }
        ushort2 o;
        o.x = f2bf((a0[0] + a1[0]) * inv);
        o.y = f2bf((a0[1] + a1[1]) * inv);
        *(ushort2*)(out + (size_t)node * D + lane * 2) = o;
    }
}

// ---------------- bf16 MFMA dual GEMM ----------------
// C = act(A0@B0 + A1@B1 + bias) (+res). A: [M][K] bf16 row-major. BT: [N][K] bf16.
// Block: 256 thr = 4 waves; tile 64(M) x 64(N); wave w owns rows w*16..w*16+15.
// mfma_f32_16x16x32_bf16 layouts (m89-verified): A/B frag: idx=lane&15,
// k=(lane>>4)*8+j ; C/D: col=lane&15, row=(lane>>4)*4+reg.
template <int RELU, int HAS_RES, int OUT_F32>
__global__ __launch_bounds__(256) void gemm_bf16(const unsigned short* __restrict__ A0,
                                                 const unsigned short* __restrict__ B0T, int K0,
                                                 const unsigned short* __restrict__ A1,
                                                 const unsigned short* __restrict__ B1T, int K1,
                                                 const float* __restrict__ bias,
                                                 const unsigned short* __restrict__ res,
                                                 void* __restrict__ Cout, int M, int N) {
    int t = threadIdx.x;
    int w = t >> 6;
    int l = t & 63;
    int l15 = l & 15, lhi = l >> 4;
    int rowBase = blockIdx.x * 64 + w * 16;
    int colBase = blockIdx.y * 64;

    f32x4 acc[4] = {f32x4{0,0,0,0}, f32x4{0,0,0,0}, f32x4{0,0,0,0}, f32x4{0,0,0,0}};

    int arow = rowBase + l15;
    if (arow >= M) arow = M - 1;   // clamp: finite garbage, store-guarded

    for (int phase = 0; phase < 2; ++phase) {
        const unsigned short* A = phase ? A1 : A0;
        const unsigned short* BT = phase ? B1T : B0T;
        int K = phase ? K1 : K0;
        if (A == nullptr) continue;
        const unsigned short* ap = A + (size_t)arow * K + lhi * 8;
        for (int k0 = 0; k0 < K; k0 += 32) {
            bf16x8 af = *(const bf16x8*)(ap + k0);
#pragma unroll
            for (int nt = 0; nt < 4; ++nt) {
                int n = colBase + nt * 16 + l15;
                bf16x8 bfr = *(const bf16x8*)(BT + (size_t)n * K + k0 + lhi * 8);
                acc[nt] = __builtin_amdgcn_mfma_f32_16x16x32_bf16(af, bfr, acc[nt], 0, 0, 0);
            }
        }
    }

#pragma unroll
    for (int nt = 0; nt < 4; ++nt) {
        int c = colBase + nt * 16 + l15;
        float bv = bias[c];
#pragma unroll
        for (int reg = 0; reg < 4; ++reg) {
            int r = rowBase + lhi * 4 + reg;
            if (r >= M) continue;
            float v = acc[nt][reg] + bv;
            if (RELU) v = fmaxf(v, 0.f);
            if (HAS_RES) v += bf2f(res[(size_t)r * N + c]);
            if (OUT_F32) ((float*)Cout)[(size_t)r * N + c] = v;
            else ((unsigned short*)Cout)[(size_t)r * N + c] = f2bf(v);
        }
    }
}

extern "C" void kernel_launch(void* const* d_in, const int* in_sizes, int n_in,
                              void* d_out, int out_size, void* d_ws, size_t ws_size,
                              hipStream_t stream) {
    const float* x    = (const float*)d_in[0];
    const void*  edges = d_in[1];
    const float* W1l  = (const float*)d_in[2];
    const float* b1   = (const float*)d_in[3];
    const float* W1r  = (const float*)d_in[4];
    const float* W2l  = (const float*)d_in[5];
    const float* b2   = (const float*)d_in[6];
    const float* W2r  = (const float*)d_in[7];
    const float* Wres = (const float*)d_in[8];
    const float* bres = (const float*)d_in[9];
    const float* Wmul = (const float*)d_in[10];
    const float* bmu  = (const float*)d_in[11];
    const float* Wmur = (const float*)d_in[12];
    const float* Wlsl = (const float*)d_in[13];
    const float* bls  = (const float*)d_in[14];
    const float* Wlsr = (const float*)d_in[15];
    float* out = (float*)d_out;

    typedef unsigned short u16;
    char* ws = (char*)d_ws;
    size_t off = 0;
    int* flag    = (int*)(ws + off); off += 256;
    int* src     = (int*)(ws + off); off += (size_t)NE * 4;
    int* dst     = (int*)(ws + off); off += (size_t)NE * 4;
    int* csr_src = (int*)(ws + off); off += (size_t)NE * 4;
    int* deg     = (int*)(ws + off); off += (size_t)NN * 4;
    int* rowptr  = (int*)(ws + off); off += (size_t)(NN + 8) * 4;
    int* cursor  = (int*)(ws + off); off += (size_t)NN * 4;
    int* incl    = (int*)(ws + off); off += (size_t)NN * 4;
    int* bsum    = (int*)(ws + off); off += 256 * 4;
    int* boff    = (int*)(ws + off); off += 256 * 4;
    off = (off + 255) & ~(size_t)255;
    u16* xb    = (u16*)(ws + off); off += (size_t)NN * 128 * 2;
    u16* agg1b = (u16*)(ws + off); off += (size_t)NN * 128 * 2;
    u16* h1b   = (u16*)(ws + off); off += (size_t)NN * 256 * 2;
    u16* xresb = (u16*)(ws + off); off += (size_t)NN * 256 * 2;
    u16* h2b   = (u16*)(ws + off); off += (size_t)NN * 256 * 2;
    u16* aggb  = (u16*)(ws + off); off += (size_t)NN * 256 * 2;   // agg2, then agg3
    u16* W1lT  = (u16*)(ws + off); off += 128 * 256 * 2;
    u16* W1rT  = (u16*)(ws + off); off += 128 * 256 * 2;
    u16* W2lT  = (u16*)(ws + off); off += 256 * 256 * 2;
    u16* W2rT  = (u16*)(ws + off); off += 256 * 256 * 2;
    u16* WresT = (u16*)(ws + off); off += 128 * 256 * 2;
    u16* WmulT = (u16*)(ws + off); off += 256 * 64 * 2;
    u16* WmurT = (u16*)(ws + off); off += 256 * 64 * 2;
    u16* WlslT = (u16*)(ws + off); off += 256 * 64 * 2;
    u16* WlsrT = (u16*)(ws + off); off += 256 * 64 * 2;

    hipMemsetAsync(flag, 0, 4, stream);
    hipMemsetAsync(deg, 0, (size_t)NN * 4, stream);
    hipMemsetAsync(cursor, 0, (size_t)NN * 4, stream);

    const int SB = (NN + 255) / 256;   // 79

    detect_kernel<<<NE / 256, 256, 0, stream>>>(edges, flag);
    convert_kernel<<<NE / 256, 256, 0, stream>>>(edges, flag, src, dst, deg);
    scan1_kernel<<<SB, 256, 0, stream>>>(deg, incl, bsum);
    scan2_kernel<<<1, 256, 0, stream>>>(bsum, boff);
    scan3_kernel<<<SB, 256, 0, stream>>>(deg, incl, boff, rowptr);
    fill_kernel<<<NE / 256, 256, 0, stream>>>(src, dst, rowptr, cursor, csr_src);

    // casts / weight transposes
    cast_kernel<<<(NN * 128 / 4 + 255) / 256, 256, 0, stream>>>(x, xb, NN * 128 / 4);
    wtrans_kernel<<<(128 * 256 + 255) / 256, 256, 0, stream>>>(W1l, W1lT, 128, 256);
    wtrans_kernel<<<(128 * 256 + 255) / 256, 256, 0, stream>>>(W1r, W1rT, 128, 256);
    wtrans_kernel<<<(256 * 256 + 255) / 256, 256, 0, stream>>>(W2l, W2lT, 256, 256);
    wtrans_kernel<<<(256 * 256 + 255) / 256, 256, 0, stream>>>(W2r, W2rT, 256, 256);
    wtrans_kernel<<<(128 * 256 + 255) / 256, 256, 0, stream>>>(Wres, WresT, 128, 256);
    wtrans_kernel<<<(256 * 64 + 255) / 256, 256, 0, stream>>>(Wmul, WmulT, 256, 64);
    wtrans_kernel<<<(256 * 64 + 255) / 256, 256, 0, stream>>>(Wmur, WmurT, 256, 64);
    wtrans_kernel<<<(256 * 64 + 255) / 256, 256, 0, stream>>>(Wlsl, WlslT, 256, 64);
    wtrans_kernel<<<(256 * 64 + 255) / 256, 256, 0, stream>>>(Wlsr, WlsrT, 256, 64);

    const int GB = (NN + 63) / 64;   // 313

    // layer 1: h1 = relu(mean(x)@W1l + b1 + x@W1r)
    aggregate_kernel<128><<<NN / 4, 256, 0, stream>>>(xb, csr_src, rowptr, agg1b);
    gemm_bf16<1, 0, 0><<<dim3(GB, 4), 256, 0, stream>>>(agg1b, W1lT, 128, xb, W1rT, 128,
                                                        b1, nullptr, h1b, NN, 256);
    // xres = x@Wres + bres
    gemm_bf16<0, 0, 0><<<dim3(GB, 4), 256, 0, stream>>>(xb, WresT, 128, nullptr, nullptr, 0,
                                                        bres, nullptr, xresb, NN, 256);
    // layer 2: h2 = relu(mean(h1)@W2l + b2 + h1@W2r) + xres
    aggregate_kernel<256><<<NN / 4, 256, 0, stream>>>(h1b, csr_src, rowptr, aggb);
    gemm_bf16<1, 1, 0><<<dim3(GB, 4), 256, 0, stream>>>(aggb, W2lT, 256, h1b, W2rT, 256,
                                                        b2, xresb, h2b, NN, 256);
    // layer 3: shared agg(h2); mu & logstd (fp32 out)
    aggregate_kernel<256><<<NN / 4, 256, 0, stream>>>(h2b, csr_src, rowptr, aggb);
    gemm_bf16<0, 0, 1><<<dim3(GB, 1), 256, 0, stream>>>(aggb, WmulT, 256, h2b, WmurT, 256,
                                                        bmu, nullptr, out, NN, 64);
    gemm_bf16<0, 0, 1><<<dim3(GB, 1), 256, 0, stream>>>(aggb, WlslT, 256, h2b, WlsrT, 256,
                                                        bls, nullptr, out + (size_t)NN * 64, NN, 64);
}

// Round 6
// 276.076 us; speedup vs baseline: 10.9175x; 1.2676x over previous
//
#include <hip/hip_runtime.h>
#include <cstddef>

#define NN 20000
#define NE 320000

typedef short bf16x8 __attribute__((ext_vector_type(8)));
typedef float f32x4 __attribute__((ext_vector_type(4)));

__device__ __forceinline__ float bf2f(unsigned short u) {
    unsigned x = ((unsigned)u) << 16;
    return __builtin_bit_cast(float, x);
}
__device__ __forceinline__ unsigned short f2bf(float f) {
    unsigned x = __builtin_bit_cast(unsigned, f);
    x = (x + 0x7fff + ((x >> 16) & 1)) >> 16;   // round-to-nearest-even
    return (unsigned short)x;
}

// ---------------- edge-index layout detection (low-contention) ----------------
// Reads all NE int64-words; any value outside [0,NN) => int32 layout.
// Block-local LDS flag -> at most one atomic per block (64 total).
__global__ __launch_bounds__(256) void detect_kernel(const void* __restrict__ edges, int* flag) {
    __shared__ int bad;
    if (threadIdx.x == 0) bad = 0;
    __syncthreads();
    int any = 0;
    for (int i = blockIdx.x * 256 + threadIdx.x; i < NE; i += 64 * 256) {
        long long v = ((const long long*)edges)[i];
        if (v < 0 || v >= NN) any = 1;
    }
    if (any) bad = 1;               // benign LDS race: all write 1
    __syncthreads();
    if (threadIdx.x == 0 && bad) atomicOr(flag, 1);
}

__global__ __launch_bounds__(256) void convert_kernel(const void* __restrict__ edges,
                                                      const int* __restrict__ flag,
                                                      int* __restrict__ src, int* __restrict__ dst,
                                                      int* __restrict__ deg) {
    int i = blockIdx.x * blockDim.x + threadIdx.x;
    if (i >= NE) return;
    int s, d;
    if (*flag) {  // int32 layout
        s = ((const int*)edges)[i];
        d = ((const int*)edges)[NE + i];
    } else {      // int64 layout
        s = (int)((const long long*)edges)[i];
        d = (int)((const long long*)edges)[NE + i];
    }
    src[i] = s;
    dst[i] = d;
    atomicAdd(&deg[d], 1);
}

// ---------------- parallel exclusive scan (3 phases) ----------------
__global__ __launch_bounds__(256) void scan1_kernel(const int* __restrict__ deg,
                                                    int* __restrict__ incl, int* __restrict__ bsum) {
    __shared__ int buf[256];
    int t = threadIdx.x, i = blockIdx.x * 256 + t;
    int v = (i < NN) ? deg[i] : 0;
    buf[t] = v;
    __syncthreads();
    for (int off = 1; off < 256; off <<= 1) {
        int u = (t >= off) ? buf[t - off] : 0;
        __syncthreads();
        buf[t] += u;
        __syncthreads();
    }
    if (i < NN) incl[i] = buf[t];
    if (t == 255) bsum[blockIdx.x] = buf[255];
}

__global__ __launch_bounds__(256) void scan2_kernel(const int* __restrict__ bsum,
                                                    int* __restrict__ boff) {
    __shared__ int buf[256];
    const int nb = (NN + 255) / 256;   // 79
    int t = threadIdx.x;
    int v = (t < nb) ? bsum[t] : 0;
    buf[t] = v;
    __syncthreads();
    for (int off = 1; off < 256; off <<= 1) {
        int u = (t >= off) ? buf[t - off] : 0;
        __syncthreads();
        buf[t] += u;
        __syncthreads();
    }
    if (t < nb) boff[t] = buf[t] - v;   // exclusive
}

__global__ __launch_bounds__(256) void scan3_kernel(const int* __restrict__ deg,
                                                    const int* __restrict__ incl,
                                                    const int* __restrict__ boff,
                                                    int* __restrict__ rowptr) {
    int i = blockIdx.x * 256 + threadIdx.x;
    if (i < NN) rowptr[i] = boff[i >> 8] + incl[i] - deg[i];
    if (i == NN) rowptr[NN] = NE;
}

// ---------------- CSR fill ----------------
__global__ __launch_bounds__(256) void fill_kernel(const int* __restrict__ src,
                                                   const int* __restrict__ dst,
                                                   const int* __restrict__ rowptr,
                                                   int* __restrict__ cursor,
                                                   int* __restrict__ csr_src) {
    int i = blockIdx.x * blockDim.x + threadIdx.x;
    if (i >= NE) return;
    int d = dst[i];
    int p = atomicAdd(&cursor[d], 1);
    csr_src[rowptr[d] + p] = src[i];
}

// ---------------- fp32 -> bf16 cast ----------------
__global__ __launch_bounds__(256) void cast_kernel(const float* __restrict__ in,
                                                   unsigned short* __restrict__ out, int n4) {
    int i = blockIdx.x * 256 + threadIdx.x;
    if (i >= n4) return;
    float4 v = *(const float4*)(in + (size_t)i * 4);
    ushort4 o;
    o.x = f2bf(v.x); o.y = f2bf(v.y); o.z = f2bf(v.z); o.w = f2bf(v.w);
    *(ushort4*)(out + (size_t)i * 4) = o;
}

// ---------------- fused weight transpose+cast: 9 jobs in one dispatch ----------------
struct WJobs {
    const float* W[9];
    unsigned short* WT[9];
    int K[9];
    int N[9];
};
__global__ __launch_bounds__(256) void wtrans_all(WJobs jobs) {
    int y = blockIdx.y;
    int K = jobs.K[y], N = jobs.N[y];
    int i = blockIdx.x * 256 + threadIdx.x;
    if (i >= K * N) return;
    int k = i / N, n = i % N;
    jobs.WT[y][(size_t)n * K + k] = f2bf(jobs.W[y][i]);
}

// ---------------- CSR mean-aggregate (bf16, 16B loads, sub-edge parallel) ----------------
// One wave per node. D=256: 2 edge-groups x 32 lanes x 16B; D=128: 4 groups x 16 lanes.
template <int D>
__global__ __launch_bounds__(256) void aggregate_kernel(const unsigned short* __restrict__ feat,
                                                        const int* __restrict__ csr_src,
                                                        const int* __restrict__ rowptr,
                                                        unsigned short* __restrict__ out) {
    int node = blockIdx.x * 4 + (threadIdx.x >> 6);
    if (node >= NN) return;
    int lane = threadIdx.x & 63;
    int beg = rowptr[node], end = rowptr[node + 1];
    int cnt = end - beg;
    float inv = 1.0f / (float)(cnt > 0 ? cnt : 1);

    constexpr int NSUB = (D == 256) ? 2 : 4;     // edge groups per wave
    constexpr int LPG = 64 / NSUB;               // lanes per group (32 or 16)
    int sub = lane / LPG;
    int c8 = lane % LPG;                          // col block: 8 bf16 = 16B

    float a[8] = {0.f, 0.f, 0.f, 0.f, 0.f, 0.f, 0.f, 0.f};
    for (int e = beg + sub; e < end; e += NSUB) {
        int s = csr_src[e];
        bf16x8 u = *(const bf16x8*)(feat + (size_t)s * D + c8 * 8);
#pragma unroll
        for (int j = 0; j < 8; j++) a[j] += bf2f((unsigned short)u[j]);
    }
    // combine edge-groups (same columns live in lanes differing by LPG)
#pragma unroll
    for (int j = 0; j < 8; j++) {
        if (NSUB == 4) a[j] += __shfl_xor(a[j], 16);
        a[j] += __shfl_xor(a[j], 32);
    }
    if (sub == 0) {
        bf16x8 o;
#pragma unroll
        for (int j = 0; j < 8; j++) o[j] = (short)f2bf(a[j] * inv);
        *(bf16x8*)(out + (size_t)node * D + c8 * 8) = o;
    }
}

// ---------------- bf16 MFMA dual GEMM ----------------
// C = act(A0@B0 + A1@B1 + bias) (+res). A: [M][K] bf16 row-major. BT: [N][K] bf16.
// mfma_f32_16x16x32_bf16 (m89-verified): A/B frag idx=lane&15, k=(lane>>4)*8+j ;
// C/D: col=lane&15, row=(lane>>4)*4+reg.
template <int RELU, int HAS_RES, int OUT_F32>
__global__ __launch_bounds__(256) void gemm_bf16(const unsigned short* __restrict__ A0,
                                                 const unsigned short* __restrict__ B0T, int K0,
                                                 const unsigned short* __restrict__ A1,
                                                 const unsigned short* __restrict__ B1T, int K1,
                                                 const float* __restrict__ bias,
                                                 const unsigned short* __restrict__ res,
                                                 void* __restrict__ Cout, int M, int N) {
    int t = threadIdx.x;
    int w = t >> 6;
    int l = t & 63;
    int l15 = l & 15, lhi = l >> 4;
    int rowBase = blockIdx.x * 64 + w * 16;
    int colBase = blockIdx.y * 64;

    f32x4 acc[4] = {f32x4{0,0,0,0}, f32x4{0,0,0,0}, f32x4{0,0,0,0}, f32x4{0,0,0,0}};

    int arow = rowBase + l15;
    if (arow >= M) arow = M - 1;   // clamp: finite garbage, store-guarded

    for (int phase = 0; phase < 2; ++phase) {
        const unsigned short* A = phase ? A1 : A0;
        const unsigned short* BT = phase ? B1T : B0T;
        int K = phase ? K1 : K0;
        if (A == nullptr) continue;
        const unsigned short* ap = A + (size_t)arow * K + lhi * 8;
        for (int k0 = 0; k0 < K; k0 += 32) {
            bf16x8 af = *(const bf16x8*)(ap + k0);
#pragma unroll
            for (int nt = 0; nt < 4; ++nt) {
                int n = colBase + nt * 16 + l15;
                bf16x8 bfr = *(const bf16x8*)(BT + (size_t)n * K + k0 + lhi * 8);
                acc[nt] = __builtin_amdgcn_mfma_f32_16x16x32_bf16(af, bfr, acc[nt], 0, 0, 0);
            }
        }
    }

#pragma unroll
    for (int nt = 0; nt < 4; ++nt) {
        int c = colBase + nt * 16 + l15;
        float bv = bias[c];
#pragma unroll
        for (int reg = 0; reg < 4; ++reg) {
            int r = rowBase + lhi * 4 + reg;
            if (r >= M) continue;
            float v = acc[nt][reg] + bv;
            if (RELU) v = fmaxf(v, 0.f);
            if (HAS_RES) v += bf2f(res[(size_t)r * N + c]);
            if (OUT_F32) ((float*)Cout)[(size_t)r * N + c] = v;
            else ((unsigned short*)Cout)[(size_t)r * N + c] = f2bf(v);
        }
    }
}

extern "C" void kernel_launch(void* const* d_in, const int* in_sizes, int n_in,
                              void* d_out, int out_size, void* d_ws, size_t ws_size,
                              hipStream_t stream) {
    const float* x    = (const float*)d_in[0];
    const void*  edges = d_in[1];
    const float* W1l  = (const float*)d_in[2];
    const float* b1   = (const float*)d_in[3];
    const float* W1r  = (const float*)d_in[4];
    const float* W2l  = (const float*)d_in[5];
    const float* b2   = (const float*)d_in[6];
    const float* W2r  = (const float*)d_in[7];
    const float* Wres = (const float*)d_in[8];
    const float* bres = (const float*)d_in[9];
    const float* Wmul = (const float*)d_in[10];
    const float* bmu  = (const float*)d_in[11];
    const float* Wmur = (const float*)d_in[12];
    const float* Wlsl = (const float*)d_in[13];
    const float* bls  = (const float*)d_in[14];
    const float* Wlsr = (const float*)d_in[15];
    float* out = (float*)d_out;

    typedef unsigned short u16;
    char* ws = (char*)d_ws;
    size_t off = 0;
    int* flag    = (int*)(ws + off); off += 256;
    int* src     = (int*)(ws + off); off += (size_t)NE * 4;
    int* dst     = (int*)(ws + off); off += (size_t)NE * 4;
    int* csr_src = (int*)(ws + off); off += (size_t)NE * 4;
    int* deg     = (int*)(ws + off); off += (size_t)NN * 4;
    int* rowptr  = (int*)(ws + off); off += (size_t)(NN + 8) * 4;
    int* cursor  = (int*)(ws + off); off += (size_t)NN * 4;
    int* incl    = (int*)(ws + off); off += (size_t)NN * 4;
    int* bsum    = (int*)(ws + off); off += 256 * 4;
    int* boff    = (int*)(ws + off); off += 256 * 4;
    off = (off + 255) & ~(size_t)255;
    u16* xb    = (u16*)(ws + off); off += (size_t)NN * 128 * 2;
    u16* agg1b = (u16*)(ws + off); off += (size_t)NN * 128 * 2;
    u16* h1b   = (u16*)(ws + off); off += (size_t)NN * 256 * 2;
    u16* xresb = (u16*)(ws + off); off += (size_t)NN * 256 * 2;
    u16* h2b   = (u16*)(ws + off); off += (size_t)NN * 256 * 2;
    u16* aggb  = (u16*)(ws + off); off += (size_t)NN * 256 * 2;   // agg2, then agg3
    u16* W1lT  = (u16*)(ws + off); off += 128 * 256 * 2;
    u16* W1rT  = (u16*)(ws + off); off += 128 * 256 * 2;
    u16* W2lT  = (u16*)(ws + off); off += 256 * 256 * 2;
    u16* W2rT  = (u16*)(ws + off); off += 256 * 256 * 2;
    u16* WresT = (u16*)(ws + off); off += 128 * 256 * 2;
    u16* WmulT = (u16*)(ws + off); off += 256 * 64 * 2;
    u16* WmurT = (u16*)(ws + off); off += 256 * 64 * 2;
    u16* WlslT = (u16*)(ws + off); off += 256 * 64 * 2;
    u16* WlsrT = (u16*)(ws + off); off += 256 * 64 * 2;

    hipMemsetAsync(flag, 0, 4, stream);
    hipMemsetAsync(deg, 0, (size_t)NN * 4, stream);
    hipMemsetAsync(cursor, 0, (size_t)NN * 4, stream);

    const int SB = (NN + 255) / 256;   // 79

    detect_kernel<<<64, 256, 0, stream>>>(edges, flag);
    convert_kernel<<<NE / 256, 256, 0, stream>>>(edges, flag, src, dst, deg);
    scan1_kernel<<<SB, 256, 0, stream>>>(deg, incl, bsum);
    scan2_kernel<<<1, 256, 0, stream>>>(bsum, boff);
    scan3_kernel<<<SB, 256, 0, stream>>>(deg, incl, boff, rowptr);
    fill_kernel<<<NE / 256, 256, 0, stream>>>(src, dst, rowptr, cursor, csr_src);

    cast_kernel<<<(NN * 128 / 4 + 255) / 256, 256, 0, stream>>>(x, xb, NN * 128 / 4);

    WJobs jobs;
    jobs.W[0] = W1l;  jobs.WT[0] = W1lT;  jobs.K[0] = 128; jobs.N[0] = 256;
    jobs.W[1] = W1r;  jobs.WT[1] = W1rT;  jobs.K[1] = 128; jobs.N[1] = 256;
    jobs.W[2] = W2l;  jobs.WT[2] = W2lT;  jobs.K[2] = 256; jobs.N[2] = 256;
    jobs.W[3] = W2r;  jobs.WT[3] = W2rT;  jobs.K[3] = 256; jobs.N[3] = 256;
    jobs.W[4] = Wres; jobs.WT[4] = WresT; jobs.K[4] = 128; jobs.N[4] = 256;
    jobs.W[5] = Wmul; jobs.WT[5] = WmulT; jobs.K[5] = 256; jobs.N[5] = 64;
    jobs.W[6] = Wmur; jobs.WT[6] = WmurT; jobs.K[6] = 256; jobs.N[6] = 64;
    jobs.W[7] = Wlsl; jobs.WT[7] = WlslT; jobs.K[7] = 256; jobs.N[7] = 64;
    jobs.W[8] = Wlsr; jobs.WT[8] = WlsrT; jobs.K[8] = 256; jobs.N[8] = 64;
    wtrans_all<<<dim3(256, 9), 256, 0, stream>>>(jobs);

    const int GB = (NN + 63) / 64;   // 313

    // layer 1: h1 = relu(mean(x)@W1l + b1 + x@W1r)
    aggregate_kernel<128><<<NN / 4, 256, 0, stream>>>(xb, csr_src, rowptr, agg1b);
    gemm_bf16<1, 0, 0><<<dim3(GB, 4), 256, 0, stream>>>(agg1b, W1lT, 128, xb, W1rT, 128,
                                                        b1, nullptr, h1b, NN, 256);
    // xres = x@Wres + bres
    gemm_bf16<0, 0, 0><<<dim3(GB, 4), 256, 0, stream>>>(xb, WresT, 128, nullptr, nullptr, 0,
                                                        bres, nullptr, xresb, NN, 256);
    // layer 2: h2 = relu(mean(h1)@W2l + b2 + h1@W2r) + xres
    aggregate_kernel<256><<<NN / 4, 256, 0, stream>>>(h1b, csr_src, rowptr, aggb);
    gemm_bf16<1, 1, 0><<<dim3(GB, 4), 256, 0, stream>>>(aggb, W2lT, 256, h1b, W2rT, 256,
                                                        b2, xresb, h2b, NN, 256);
    // layer 3: shared agg(h2); mu & logstd (fp32 out)
    aggregate_kernel<256><<<NN / 4, 256, 0, stream>>>(h2b, csr_src, rowptr, aggb);
    gemm_bf16<0, 0, 1><<<dim3(GB, 1), 256, 0, stream>>>(aggb, WmulT, 256, h2b, WmurT, 256,
                                                        bmu, nullptr, out, NN, 64);
    gemm_bf16<0, 0, 1><<<dim3(GB, 1), 256, 0, stream>>>(aggb, WlslT, 256, h2b, WlsrT, 256,
                                                        bls, nullptr, out + (size_t)NN * 64, NN, 64);
}